// Round 8
// baseline (1064.652 us; speedup 1.0000x reference)
//
#include <hip/hip_runtime.h>

#define N_NODES 10000
#define N_EDGES 50000
#define IN0     32
#define EDGE_IN 16
#define GIN     8
#define HID     64
#define NG      64
#define KDIM    128
#define BV      32        // virtual nodes per fused block
#define NVMAX   12500     // sum ceil(deg/16) <= (E + 15*N)/16
#define EPS     1e-5f

typedef _Float16 f16;
typedef _Float16 v8h __attribute__((ext_vector_type(8)));
typedef float    v4f __attribute__((ext_vector_type(4)));

// ---------------------------------------------------------------------------
// htp[einv[e]][j] = f16(relu(ea[e]@w1[:,j] + b1[j]))  -- row-per-edge layout,
// rows permuted into src-CSR order so the fused app-phase reads are coalesced.
__global__ __launch_bounds__(256) void ht_kernel(const float* __restrict__ ea,
                                                 const float* __restrict__ w1,
                                                 const float* __restrict__ b1,
                                                 const int* __restrict__ einv,
                                                 f16* __restrict__ htp) {
    __shared__ float eas[128][17];
    __shared__ f16 hl[128][136];      // 128 k-rows padded to 136 (16B-aligned rows)
    const int e0 = blockIdx.x * 128, t = threadIdx.x;
    for (int idx = t; idx < 128 * 16; idx += 256) {
        int r = idx >> 4, i = idx & 15;
        eas[r][i] = (e0 + r < N_EDGES) ? ea[(size_t)(e0 + r) * EDGE_IN + i] : 0.f;
    }
    __syncthreads();
    const int el = t & 127, jh = t >> 7;
#pragma unroll 1
    for (int jj = 0; jj < 64; jj++) {
        const int j = jh * 64 + jj;
        float acc = b1[j];
#pragma unroll
        for (int i = 0; i < EDGE_IN; i++) acc += eas[el][i] * w1[i * KDIM + j];
        hl[el][j] = (f16)fmaxf(acc, 0.f);
    }
    __syncthreads();
    for (int idx = t; idx < 128 * 16; idx += 256) {     // 16 uint4 per 128-f16 row
        const int row = idx >> 4, sg = idx & 15;
        if (e0 + row < N_EDGES) {
            uint4* dp = (uint4*)(htp + (size_t)einv[e0 + row] * KDIM) + sg;
            *dp = *((const uint4*)(&hl[row][0]) + sg);
        }
    }
}

// ---------------------------------------------------------------------------
// xf[idx] = f16(x[idx])
__global__ __launch_bounds__(256) void xconv(const float* __restrict__ x,
                                             f16* __restrict__ xf, int n) {
    int idx = blockIdx.x * 256 + threadIdx.x;
    if (idx < n) xf[idx] = (f16)x[idx];
}

// ---------------------------------------------------------------------------
// Bg2[C'][i], C' = o*128 + k (k minor!) for k<128: w2[k][i*64+o];
// rows 8192+o: b2[i*64+o] (the per-node bias term ub). f16.
__global__ __launch_bounds__(256) void bconv(const float* __restrict__ w2,
                                             const float* __restrict__ b2,
                                             f16* __restrict__ Bg2,
                                             int inshift) {
    const int in = 1 << inshift;
    const int total = 8256 << inshift;
    int idx = blockIdx.x * 256 + threadIdx.x;
    if (idx >= total) return;
    const int i = idx & (in - 1), C = idx >> inshift;
    float v;
    if (C < 8192) {
        const int k = C & 127, o = C >> 7;
        v = w2[(size_t)k * (in << 6) + (i << 6) + o];
    } else {
        const int o = C - 8192;
        v = b2[(i << 6) + o];
    }
    Bg2[idx] = (f16)v;
}

// ---------------------------------------------------------------------------
// CSR over SRC (constant across layers; built once) + virtual-node list:
// vnode = (node, 16-edge subrange). nv <= NVMAX.
__global__ __launch_bounds__(256) void csr_count(const int* __restrict__ src,
                                                 int* __restrict__ cnt) {
    int e = blockIdx.x * 256 + threadIdx.x;
    if (e < N_EDGES) atomicAdd(&cnt[src[e]], 1);
}

__global__ __launch_bounds__(256) void csr_scan(const int* __restrict__ cnt,
                                                int* __restrict__ row_ptr,
                                                int* __restrict__ cursor,
                                                int* __restrict__ vn_node,
                                                int* __restrict__ vn_rb,
                                                int* __restrict__ nvp) {
    __shared__ int part[256], psum[257];
    __shared__ int vpart[256], vpsum[257];
    const int t = threadIdx.x;
    const int base = t * 40;                       // 256*40 >= 10000
    int s = 0, vs = 0;
    for (int i = 0; i < 40; i++) {
        int idx = base + i;
        if (idx < N_NODES) { int d = cnt[idx]; s += d; vs += (d + 15) >> 4; }
    }
    part[t] = s; vpart[t] = vs;
    __syncthreads();
    if (t == 0) {
        int run = 0, vrun = 0;
        for (int i = 0; i < 256; i++) {
            psum[i] = run;  run += part[i];
            vpsum[i] = vrun; vrun += vpart[i];
        }
        psum[256] = run; vpsum[256] = vrun;
    }
    __syncthreads();
    int run = psum[t], vrun = vpsum[t];
    for (int i = 0; i < 40; i++) {
        int idx = base + i;
        if (idx < N_NODES) {
            int d = cnt[idx];
            row_ptr[idx] = run; cursor[idx] = run;
            int nvn = (d + 15) >> 4;
            for (int j = 0; j < nvn; j++) {
                vn_node[vrun] = idx; vn_rb[vrun] = run + j * 16; vrun++;
            }
            run += d;
        }
    }
    if (t == 255) { row_ptr[N_NODES] = psum[256]; *nvp = vpsum[256]; }
}

__global__ __launch_bounds__(256) void csr_fill(const int* __restrict__ src,
                                                int* __restrict__ cursor,
                                                int* __restrict__ eix,
                                                int* __restrict__ einv) {
    int e = blockIdx.x * 256 + threadIdx.x;
    if (e < N_EDGES) {
        int p = atomicAdd(&cursor[src[e]], 1);
        eix[p] = e;
        einv[e] = p;
    }
}

// ---------------------------------------------------------------------------
// Node-factored NNConv:
//   T[n,k,o] = sum_i xf[n,i] * w2[k,i,o]      (per-node, NOT per-edge: 5x fewer FLOPs)
//   msg[e,o] = sum_k ht[e,k] * T[src,k,o] + ub[src,o];  agg[dst] += msg (atomics)
// Block = 32 vnode SLOTS (tcs/ubs are indexed by slot 0..31, never by global
// node id -- that mixup was R7's correctness bug). K streamed in 8 chunks of
// 16 k via LDS tcs (f16, 64KB).
__global__ __launch_bounds__(256, 1) void fused_msg2(const f16* __restrict__ htp,
                                                     const f16* __restrict__ xf,
                                                     const f16* __restrict__ Bg2,
                                                     const int* __restrict__ eix,
                                                     const int* __restrict__ row_ptr,
                                                     const int* __restrict__ vn_node,
                                                     const int* __restrict__ vn_rb,
                                                     const int* __restrict__ dst,
                                                     float* __restrict__ agg,
                                                     const int* __restrict__ nvp,
                                                     int inshift) {
    __shared__ f16 tcs[BV * 1024 + 32];   // [slot][(o^(slot&3))][k16] + overrun pad
    __shared__ f16 ubs[BV * 68];          // [slot][o] row-padded 64->68
    __shared__ int snd[BV], srb[BV], sct[BV];

    const int t = threadIdx.x;
    const int w = t >> 6, lane = t & 63;
    const int m = lane & 15, q = lane >> 4;
    const int v0 = blockIdx.x * BV;
    const int nv = *nvp;
    if (v0 >= nv) return;
    const bool in64 = (inshift == 6);

    for (int i = t; i < BV; i += 256) {
        int v = v0 + i, n = 0, rb = 0, ct = 0;
        if (v < nv) {
            n = vn_node[v]; rb = vn_rb[v];
            int re = row_ptr[n + 1];
            ct = re - rb; if (ct > 16) ct = 16;
        }
        snd[i] = n; srb[i] = rb; sct[i] = ct;
    }
    __syncthreads();

    // T-phase B-fragments (xf rows of this block's vnode slots) -- fixed all kernel
    v8h bfx[2][2];
#pragma unroll
    for (int h = 0; h < 2; h++) {
        const size_t nb = (size_t)snd[(h << 4) + m] << inshift;
        bfx[h][0] = *(const v8h*)(xf + nb + q * 8);
        if (in64) bfx[h][1] = *(const v8h*)(xf + nb + 32 + q * 8);
    }

    v4f acc[8][4];
#pragma unroll
    for (int j = 0; j < 8; j++)
#pragma unroll
        for (int ot = 0; ot < 4; ot++) acc[j][ot] = (v4f){0.f, 0.f, 0.f, 0.f};

    for (int c = 0; c < 8; c++) {
        // ---- T-phase: wave computes o in [w*16, w*16+16), both slot-halves.
        // D (16x16): row=q*4+reg -> k within chunk, col=m -> slot(+16h).
#pragma unroll 4
        for (int ol = 0; ol < 16; ol++) {
            const int o = (w << 4) + ol;
            const size_t arow = ((size_t)(o * 128 + c * 16 + m)) << inshift;
            v8h a0 = *(const v8h*)(Bg2 + arow + q * 8);
            v8h a1;
            if (in64) a1 = *(const v8h*)(Bg2 + arow + 32 + q * 8);
#pragma unroll
            for (int h = 0; h < 2; h++) {
                v4f d = (v4f){0.f, 0.f, 0.f, 0.f};
                d = __builtin_amdgcn_mfma_f32_16x16x32_f16(a0, bfx[h][0], d, 0, 0, 0);
                if (in64)
                    d = __builtin_amdgcn_mfma_f32_16x16x32_f16(a1, bfx[h][1], d, 0, 0, 0);
                const int sl = (h << 4) + m;          // SLOT index
                union { f16 x[4]; uint2 u; } pk;
                pk.x[0] = (f16)d[0]; pk.x[1] = (f16)d[1];
                pk.x[2] = (f16)d[2]; pk.x[3] = (f16)d[3];
                *(uint2*)(tcs + sl * 1024 + ((o ^ (sl & 3)) << 4) + (q << 2)) = pk.u;
            }
        }
        __syncthreads();
        // ---- app-phase: wave applies its 8 vnode slots' edges
#pragma unroll
        for (int j = 0; j < 8; j++) {
            const int vn = (w << 3) + j;              // SLOT index 0..31
            const int rb = srb[vn], ct = sct[vn];
            const int es = (m < ct) ? m : (ct > 0 ? ct - 1 : 0);
            v8h ha;
#pragma unroll
            for (int z = 0; z < 8; z++) ha[z] = (f16)0.f;
            if (q < 2)      // lanes q>=2 are k 16..31 of the MFMA: zero (K=16 pad)
                ha = *(const v8h*)(htp + (size_t)(rb + es) * KDIM + c * 16 + q * 8);
            const f16* tb = tcs + vn * 1024;
            const int nx = vn & 3;
#pragma unroll
            for (int ot = 0; ot < 4; ot++) {
                v8h hb = *(const v8h*)(tb + ((((ot << 4) + m) ^ nx) << 4) + (q << 3));
                acc[j][ot] = __builtin_amdgcn_mfma_f32_16x16x32_f16(ha, hb, acc[j][ot], 0, 0, 0);
            }
        }
        __syncthreads();
    }

    // ---- ub mini-chunk: ub[slot][o] = sum_i xf[n,i] b2[i,o] (Bg2 rows 8192+o)
    {
        const size_t arow = ((size_t)(8192 + (w << 4) + m)) << inshift;
        v8h a0 = *(const v8h*)(Bg2 + arow + q * 8);
        v8h a1;
        if (in64) a1 = *(const v8h*)(Bg2 + arow + 32 + q * 8);
#pragma unroll
        for (int h = 0; h < 2; h++) {
            v4f d = (v4f){0.f, 0.f, 0.f, 0.f};
            d = __builtin_amdgcn_mfma_f32_16x16x32_f16(a0, bfx[h][0], d, 0, 0, 0);
            if (in64)
                d = __builtin_amdgcn_mfma_f32_16x16x32_f16(a1, bfx[h][1], d, 0, 0, 0);
            const int sl = (h << 4) + m;              // SLOT index
            union { f16 x[4]; uint2 u; } pk;
            pk.x[0] = (f16)d[0]; pk.x[1] = (f16)d[1];
            pk.x[2] = (f16)d[2]; pk.x[3] = (f16)d[3];
            *(uint2*)(ubs + sl * 68 + (w << 4) + (q << 2)) = pk.u;
        }
    }
    __syncthreads();

    // ---- epilogue: scatter acc + ub into agg by dst (f32 atomics)
#pragma unroll
    for (int j = 0; j < 8; j++) {
        const int vn = (w << 3) + j;                  // SLOT index
        const int rb = srb[vn], ct = sct[vn];
        if (ct == 0) continue;                        // wave-uniform
        int dr[4];
#pragma unroll
        for (int r = 0; r < 4; r++) {
            const int es = (q << 2) + r;
            dr[r] = (es < ct) ? dst[eix[rb + es]] : -1;
        }
#pragma unroll
        for (int ot = 0; ot < 4; ot++) {
            const float ub = (float)ubs[vn * 68 + (ot << 4) + m];
#pragma unroll
            for (int r = 0; r < 4; r++)
                if (dr[r] >= 0)
                    atomicAdd(&agg[(size_t)dr[r] * 64 + (ot << 4) + m],
                              acc[j][ot][r] + ub);
        }
    }
}

// ---------------------------------------------------------------------------
// pre[n,o] = agg[n,o] + sum_i x[n,i]*root[i,o] + bias[o]; accumulate BN stats.
__global__ __launch_bounds__(256) void pre_stats(const float* __restrict__ agg,
                                                 const float* __restrict__ x,
                                                 const float* __restrict__ root,
                                                 const float* __restrict__ bias,
                                                 float* __restrict__ pre,
                                                 float* __restrict__ stats,
                                                 int in, int inshift) {
    __shared__ float xs[4][64];
    __shared__ float lsum[64], lsq[64];
    const int o = threadIdx.x & 63, nl = threadIdx.x >> 6;
    if (threadIdx.x < 64) { lsum[threadIdx.x] = 0.f; lsq[threadIdx.x] = 0.f; }
    const float bo = bias[o];
    for (int n0 = blockIdx.x * 4; n0 < N_NODES; n0 += gridDim.x * 4) {
        __syncthreads();
        for (int idx = threadIdx.x; idx < (4 << inshift); idx += 256) {
            int r = idx >> inshift, i = idx & (in - 1);
            if (n0 + r < N_NODES) xs[r][i] = x[(size_t)(n0 + r) * in + i];
        }
        __syncthreads();
        int n = n0 + nl;
        if (n < N_NODES) {
            float acc = agg[(size_t)n * 64 + o] + bo;
#pragma unroll 8
            for (int i = 0; i < in; i++) acc += xs[nl][i] * root[i * 64 + o];
            pre[(size_t)n * 64 + o] = acc;
            atomicAdd(&lsum[o], acc);
            atomicAdd(&lsq[o], acc * acc);
        }
    }
    __syncthreads();
    if (threadIdx.x < 64) {
        atomicAdd(&stats[threadIdx.x], lsum[threadIdx.x]);
        atomicAdd(&stats[64 + threadIdx.x], lsq[threadIdx.x]);
    }
}

// ---------------------------------------------------------------------------
// BN (batch stats, biased var) + ReLU. mode 0: store xn. mode 1: segment-max pool.
__global__ __launch_bounds__(256) void bn_apply(const float* __restrict__ pre,
                                                const float* __restrict__ stats,
                                                const float* __restrict__ gamma,
                                                const float* __restrict__ beta,
                                                float* __restrict__ xn,
                                                const int* __restrict__ batch,
                                                float* __restrict__ pooled,
                                                int mode) {
    int idx = blockIdx.x * 256 + threadIdx.x;
    if (idx >= N_NODES * 64) return;
    const int o = idx & 63, n = idx >> 6;
    const float inv = 1.f / (float)N_NODES;
    float mu = stats[o] * inv;
    float var = stats[64 + o] * inv - mu * mu;
    float sc = gamma[o] * rsqrtf(var + EPS);
    float sh = beta[o] - mu * sc;
    float v = fmaxf(pre[idx] * sc + sh, 0.f);
    if (mode == 0) xn[idx] = v;
    else atomicMax((int*)&pooled[(size_t)batch[n] * 64 + o], __float_as_int(v));
}

// ---------------------------------------------------------------------------
// out[g] = pp_b2 + relu(cat(pooled[g],u[g]) @ pp_w1 + pp_b1) @ pp_w2
__global__ __launch_bounds__(64) void final_mlp(const float* __restrict__ pooled,
                                                const float* __restrict__ u,
                                                const float* __restrict__ w1,
                                                const float* __restrict__ b1,
                                                const float* __restrict__ w2,
                                                const float* __restrict__ b2,
                                                float* __restrict__ out) {
    const int g = blockIdx.x, t = threadIdx.x;
    float acc = b1[t];
#pragma unroll 8
    for (int i = 0; i < 64; i++) acc += pooled[g * 64 + i] * w1[i * 64 + t];
#pragma unroll
    for (int j = 0; j < GIN; j++) acc += u[g * GIN + j] * w1[(64 + j) * 64 + t];
    float hv = fmaxf(acc, 0.f) * w2[t];
#pragma unroll
    for (int off = 32; off > 0; off >>= 1) hv += __shfl_down(hv, off, 64);
    if (t == 0) out[g] = hv + b2[0];
}

// ---------------------------------------------------------------------------
extern "C" void kernel_launch(void* const* d_in, const int* in_sizes, int n_in,
                              void* d_out, int out_size, void* d_ws, size_t ws_size,
                              hipStream_t stream) {
    const float* x0      = (const float*)d_in[0];
    const int*   ei      = (const int*)d_in[1];
    const int*   src     = ei;
    const int*   dst     = ei + N_EDGES;
    const float* ea      = (const float*)d_in[2];
    const int*   batch   = (const int*)d_in[3];
    const float* u       = (const float*)d_in[4];
    const float* e0w1    = (const float*)d_in[5];
    const float* e0b1    = (const float*)d_in[6];
    const float* e0w2    = (const float*)d_in[7];
    const float* e0b2    = (const float*)d_in[8];
    const float* root0   = (const float*)d_in[9];
    const float* bias0   = (const float*)d_in[10];
    const float* gamma0  = (const float*)d_in[11];
    const float* beta0   = (const float*)d_in[12];
    const float* ew1     = (const float*)d_in[13];
    const float* eb1     = (const float*)d_in[14];
    const float* ew2     = (const float*)d_in[15];
    const float* eb2     = (const float*)d_in[16];
    const float* rootl   = (const float*)d_in[17];
    const float* biasl   = (const float*)d_in[18];
    const float* gammal  = (const float*)d_in[19];
    const float* betal   = (const float*)d_in[20];
    const float* pp_w1   = (const float*)d_in[21];
    const float* pp_b1   = (const float*)d_in[22];
    const float* pp_w2   = (const float*)d_in[23];
    const float* pp_b2   = (const float*)d_in[24];

    float* ws = (float*)d_ws;
    size_t off = 0;
    f16*   htp    = (f16*)(ws + off); off += (size_t)N_EDGES * KDIM / 2;
    f16*   xf     = (f16*)(ws + off); off += (size_t)N_NODES * 64 / 2;
    f16*   Bg2    = (f16*)(ws + off); off += (size_t)8256 * 64 / 2;
    float* agg    = ws + off; off += (size_t)N_NODES * 64;
    float* xa     = ws + off; off += (size_t)N_NODES * 64;
    float* xb     = ws + off; off += (size_t)N_NODES * 64;
    float* stats  = ws + off; off += 256;
    float* pooled = ws + off; off += (size_t)NG * 64;
    int*   row_ptr = (int*)(ws + off); off += 10008;
    int*   cursor  = (int*)(ws + off); off += 10000;
    int*   cnt     = (int*)(ws + off); off += 10000;
    int*   eix     = (int*)(ws + off); off += N_EDGES;
    int*   einv    = (int*)(ws + off); off += N_EDGES;
    int*   vn_node = (int*)(ws + off); off += NVMAX + 12;
    int*   vn_rb   = (int*)(ws + off); off += NVMAX + 12;
    int*   nvp     = (int*)(ws + off); off += 8;

    hipMemsetAsync(pooled, 0, (size_t)NG * 64 * 4, stream);

    const int eblocks = (N_EDGES + 255) / 256;               // 196
    const int hblocks = (N_EDGES + 127) / 128;               // 391
    const int fblocks = (NVMAX + BV - 1) / BV;               // 391 (early-exit past nv)
    const int ablocks = (N_NODES * 64 + 255) / 256;

    // src-CSR + vnode list: built once, reused by all 4 layers
    hipMemsetAsync(cnt, 0, N_NODES * 4, stream);
    csr_count<<<eblocks, 256, 0, stream>>>(src, cnt);
    csr_scan<<<1, 256, 0, stream>>>(cnt, row_ptr, cursor, vn_node, vn_rb, nvp);
    csr_fill<<<eblocks, 256, 0, stream>>>(src, cursor, eix, einv);

    struct Layer {
        const float *w1, *b1, *w2, *b2, *root, *bias, *gamma, *beta, *xin;
        float* xout; int in, inshift, mode;
    };
    Layer L[4];
    L[0] = {e0w1, e0b1, e0w2, e0b2, root0, bias0, gamma0, beta0, x0, xa, IN0, 5, 0};
    for (int l = 0; l < 3; l++) {
        const float* xin  = (l == 0) ? xa : ((l == 1) ? xb : xa);
        float*       xout = (l == 0) ? xb : ((l == 1) ? xa : nullptr);
        L[l + 1] = {ew1 + (size_t)l * EDGE_IN * KDIM, eb1 + (size_t)l * KDIM,
                    ew2 + (size_t)l * KDIM * (HID * HID), eb2 + (size_t)l * (HID * HID),
                    rootl + (size_t)l * HID * HID, biasl + (size_t)l * HID,
                    gammal + (size_t)l * HID, betal + (size_t)l * HID,
                    xin, xout, HID, 6, (l == 2) ? 1 : 0};
    }

    for (int l = 0; l < 4; l++) {
        const Layer& P = L[l];
        const int bblocks = ((8256 << P.inshift) + 255) / 256;
        ht_kernel<<<hblocks, 256, 0, stream>>>(ea, P.w1, P.b1, einv, htp);
        xconv<<<(N_NODES * P.in + 255) / 256, 256, 0, stream>>>(P.xin, xf, N_NODES * P.in);
        bconv<<<bblocks, 256, 0, stream>>>(P.w2, P.b2, Bg2, P.inshift);
        hipMemsetAsync(agg, 0, (size_t)N_NODES * 64 * 4, stream);
        hipMemsetAsync(stats, 0, 128 * 4, stream);
        fused_msg2<<<fblocks, 256, 0, stream>>>(htp, xf, Bg2, eix, row_ptr,
                                                vn_node, vn_rb, dst, agg, nvp,
                                                P.inshift);
        pre_stats<<<512, 256, 0, stream>>>(agg, P.xin, P.root, P.bias, agg, stats,
                                           P.in, P.inshift);
        bn_apply<<<ablocks, 256, 0, stream>>>(agg, stats, P.gamma, P.beta, P.xout,
                                              batch, pooled, P.mode);
    }
    final_mlp<<<NG, 64, 0, stream>>>(pooled, u, pp_w1, pp_b1, pp_w2, pp_b2,
                                     (float*)d_out);
}

// Round 10
// 859.715 us; speedup vs baseline: 1.2384x; 1.2384x over previous
//
#include <hip/hip_runtime.h>

#define N_NODES 10000
#define N_EDGES 50000
#define IN0     32
#define EDGE_IN 16
#define GIN     8
#define HID     64
#define NG      64
#define KDIM    128
#define BV      16        // virtual nodes per fused block (halved from R8 for occupancy)
#define NVMAX   12500     // sum ceil(deg/16) <= (E + 15*N)/16
#define EPS     1e-5f

typedef _Float16 f16;
typedef _Float16 v8h __attribute__((ext_vector_type(8)));
typedef float    v4f __attribute__((ext_vector_type(4)));

// ---------------------------------------------------------------------------
// htp[einv[e]][j] = f16(relu(ea[e]@w1[:,j] + b1[j]))  -- row-per-edge layout,
// rows permuted into src-CSR order so the fused app-phase reads are coalesced.
__global__ __launch_bounds__(256) void ht_kernel(const float* __restrict__ ea,
                                                 const float* __restrict__ w1,
                                                 const float* __restrict__ b1,
                                                 const int* __restrict__ einv,
                                                 f16* __restrict__ htp) {
    __shared__ float eas[128][17];
    __shared__ f16 hl[128][136];      // 128 k-rows padded to 136 (16B-aligned rows)
    const int e0 = blockIdx.x * 128, t = threadIdx.x;
    for (int idx = t; idx < 128 * 16; idx += 256) {
        int r = idx >> 4, i = idx & 15;
        eas[r][i] = (e0 + r < N_EDGES) ? ea[(size_t)(e0 + r) * EDGE_IN + i] : 0.f;
    }
    __syncthreads();
    const int el = t & 127, jh = t >> 7;
#pragma unroll 1
    for (int jj = 0; jj < 64; jj++) {
        const int j = jh * 64 + jj;
        float acc = b1[j];
#pragma unroll
        for (int i = 0; i < EDGE_IN; i++) acc += eas[el][i] * w1[i * KDIM + j];
        hl[el][j] = (f16)fmaxf(acc, 0.f);
    }
    __syncthreads();
    for (int idx = t; idx < 128 * 16; idx += 256) {     // 16 uint4 per 128-f16 row
        const int row = idx >> 4, sg = idx & 15;
        if (e0 + row < N_EDGES) {
            uint4* dp = (uint4*)(htp + (size_t)einv[e0 + row] * KDIM) + sg;
            *dp = *((const uint4*)(&hl[row][0]) + sg);
        }
    }
}

// ---------------------------------------------------------------------------
// xf[idx] = f16(x[idx])
__global__ __launch_bounds__(256) void xconv(const float* __restrict__ x,
                                             f16* __restrict__ xf, int n) {
    int idx = blockIdx.x * 256 + threadIdx.x;
    if (idx < n) xf[idx] = (f16)x[idx];
}

// ---------------------------------------------------------------------------
// Bg2[C'][i], C' = o*128 + k (k minor!) for k<128: w2[k][i*64+o];
// rows 8192+o: b2[i*64+o] (the per-node bias term ub). f16.
__global__ __launch_bounds__(256) void bconv(const float* __restrict__ w2,
                                             const float* __restrict__ b2,
                                             f16* __restrict__ Bg2,
                                             int inshift) {
    const int in = 1 << inshift;
    const int total = 8256 << inshift;
    int idx = blockIdx.x * 256 + threadIdx.x;
    if (idx >= total) return;
    const int i = idx & (in - 1), C = idx >> inshift;
    float v;
    if (C < 8192) {
        const int k = C & 127, o = C >> 7;
        v = w2[(size_t)k * (in << 6) + (i << 6) + o];
    } else {
        const int o = C - 8192;
        v = b2[(i << 6) + o];
    }
    Bg2[idx] = (f16)v;
}

// ---------------------------------------------------------------------------
// CSR over SRC (constant across layers; built once) + virtual-node list:
// vnode = (node, 16-edge subrange). nv <= NVMAX.
__global__ __launch_bounds__(256) void csr_count(const int* __restrict__ src,
                                                 int* __restrict__ cnt) {
    int e = blockIdx.x * 256 + threadIdx.x;
    if (e < N_EDGES) atomicAdd(&cnt[src[e]], 1);
}

__global__ __launch_bounds__(256) void csr_scan(const int* __restrict__ cnt,
                                                int* __restrict__ row_ptr,
                                                int* __restrict__ cursor,
                                                int* __restrict__ vn_node,
                                                int* __restrict__ vn_rb,
                                                int* __restrict__ nvp) {
    __shared__ int part[256], psum[257];
    __shared__ int vpart[256], vpsum[257];
    const int t = threadIdx.x;
    const int base = t * 40;                       // 256*40 >= 10000
    int s = 0, vs = 0;
    for (int i = 0; i < 40; i++) {
        int idx = base + i;
        if (idx < N_NODES) { int d = cnt[idx]; s += d; vs += (d + 15) >> 4; }
    }
    part[t] = s; vpart[t] = vs;
    __syncthreads();
    if (t == 0) {
        int run = 0, vrun = 0;
        for (int i = 0; i < 256; i++) {
            psum[i] = run;  run += part[i];
            vpsum[i] = vrun; vrun += vpart[i];
        }
        psum[256] = run; vpsum[256] = vrun;
    }
    __syncthreads();
    int run = psum[t], vrun = vpsum[t];
    for (int i = 0; i < 40; i++) {
        int idx = base + i;
        if (idx < N_NODES) {
            int d = cnt[idx];
            row_ptr[idx] = run; cursor[idx] = run;
            int nvn = (d + 15) >> 4;
            for (int j = 0; j < nvn; j++) {
                vn_node[vrun] = idx; vn_rb[vrun] = run + j * 16; vrun++;
            }
            run += d;
        }
    }
    if (t == 255) { row_ptr[N_NODES] = psum[256]; *nvp = vpsum[256]; }
}

__global__ __launch_bounds__(256) void csr_fill(const int* __restrict__ src,
                                                int* __restrict__ cursor,
                                                int* __restrict__ eix,
                                                int* __restrict__ einv) {
    int e = blockIdx.x * 256 + threadIdx.x;
    if (e < N_EDGES) {
        int p = atomicAdd(&cursor[src[e]], 1);
        eix[p] = e;
        einv[e] = p;
    }
}

// ---------------------------------------------------------------------------
// Node-factored NNConv (exact R8-passing indexing, h-dimension specialized to
// h=0: BV 32->16, slot sl = m, vn = w*4+j; tcs layout and XOR swizzle
// byte-identical to the verified version):
//   T[n,k,o] = sum_i xf[n,i] * w2[k,i,o]
//   msg[e,o] = sum_k ht[e,k] * T[src,k,o] + ub[src,o];  agg[dst] += msg
__global__ __launch_bounds__(256, 1) void fused_msg2(const f16* __restrict__ htp,
                                                     const f16* __restrict__ xf,
                                                     const f16* __restrict__ Bg2,
                                                     const int* __restrict__ eix,
                                                     const int* __restrict__ row_ptr,
                                                     const int* __restrict__ vn_node,
                                                     const int* __restrict__ vn_rb,
                                                     const int* __restrict__ dst,
                                                     float* __restrict__ agg,
                                                     const int* __restrict__ nvp,
                                                     int inshift) {
    __shared__ f16 tcs[BV * 1024 + 32];   // [slot][(o^(slot&3))][k16] + tail pad (~32.8KB)
    __shared__ f16 ubs[BV * 68];          // [slot][o] row-padded 64->68
    __shared__ int snd[BV], srb[BV], sct[BV];

    const int t = threadIdx.x;
    const int w = t >> 6, lane = t & 63;
    const int m = lane & 15, q = lane >> 4;
    const int v0 = blockIdx.x * BV;
    const int nv = *nvp;
    if (v0 >= nv) return;
    const bool in64 = (inshift == 6);

    for (int i = t; i < BV; i += 256) {
        int v = v0 + i, n = 0, rb = 0, ct = 0;
        if (v < nv) {
            n = vn_node[v]; rb = vn_rb[v];
            int re = row_ptr[n + 1];
            ct = re - rb; if (ct > 16) ct = 16;
        }
        snd[i] = n; srb[i] = rb; sct[i] = ct;
    }
    // zero the tail pad (read by vn=BV-1, q>=2 lanes with zero-A; stale-LDS NaN
    // would poison 0*x)
    if (t < 8) *(uint2*)(tcs + BV * 1024 + t * 4) = (uint2){0u, 0u};
    __syncthreads();

    // T-phase B-fragment: xf row of slot m (N dim = the 16 slots)
    v8h bfx[2];
    {
        const size_t nb = (size_t)snd[m] << inshift;
        bfx[0] = *(const v8h*)(xf + nb + q * 8);
        if (in64) bfx[1] = *(const v8h*)(xf + nb + 32 + q * 8);
    }

    v4f acc[4][4];
#pragma unroll
    for (int j = 0; j < 4; j++)
#pragma unroll
        for (int ot = 0; ot < 4; ot++) acc[j][ot] = (v4f){0.f, 0.f, 0.f, 0.f};

    for (int c = 0; c < 8; c++) {
        // ---- T-phase: wave w computes o in [w*16, w*16+16), all 16 slots.
        // D (16x16): row = q*4+reg -> k within chunk, col = m -> slot.
#pragma unroll 4
        for (int ol = 0; ol < 16; ol++) {
            const int o = (w << 4) + ol;
            const size_t arow = ((size_t)(o * 128 + (c << 4) + m)) << inshift;
            v8h a0 = *(const v8h*)(Bg2 + arow + q * 8);
            v8h a1;
            if (in64) a1 = *(const v8h*)(Bg2 + arow + 32 + q * 8);
            v4f d = (v4f){0.f, 0.f, 0.f, 0.f};
            d = __builtin_amdgcn_mfma_f32_16x16x32_f16(a0, bfx[0], d, 0, 0, 0);
            if (in64)
                d = __builtin_amdgcn_mfma_f32_16x16x32_f16(a1, bfx[1], d, 0, 0, 0);
            const int sl = m;                         // SLOT index
            union { f16 x[4]; uint2 u; } pk;
            pk.x[0] = (f16)d[0]; pk.x[1] = (f16)d[1];
            pk.x[2] = (f16)d[2]; pk.x[3] = (f16)d[3];
            *(uint2*)(tcs + sl * 1024 + ((o ^ (sl & 3)) << 4) + (q << 2)) = pk.u;
        }
        __syncthreads();
        // ---- app-phase: wave w applies vnode slots w*4 .. w*4+3
#pragma unroll
        for (int j = 0; j < 4; j++) {
            const int vn = (w << 2) + j;              // SLOT index 0..15
            const int rb = srb[vn], ct = sct[vn];
            const int es = (m < ct) ? m : (ct > 0 ? ct - 1 : 0);
            v8h ha;
#pragma unroll
            for (int z = 0; z < 8; z++) ha[z] = (f16)0.f;
            if (q < 2)      // lanes q>=2 are k 16..31 of the MFMA: zero (K=16 pad)
                ha = *(const v8h*)(htp + (size_t)(rb + es) * KDIM + (c << 4) + q * 8);
            const f16* tb = tcs + vn * 1024;
            const int nx = vn & 3;
#pragma unroll
            for (int ot = 0; ot < 4; ot++) {
                v8h hb = *(const v8h*)(tb + ((((ot << 4) + m) ^ nx) << 4) + (q << 3));
                acc[j][ot] = __builtin_amdgcn_mfma_f32_16x16x32_f16(ha, hb, acc[j][ot], 0, 0, 0);
            }
        }
        __syncthreads();
    }

    // ---- ub mini-chunk: ub[slot][o] = sum_i xf[n,i] b2[i,o] (Bg2 rows 8192+o)
    {
        const size_t arow = ((size_t)(8192 + (w << 4) + m)) << inshift;
        v8h a0 = *(const v8h*)(Bg2 + arow + q * 8);
        v4f d = (v4f){0.f, 0.f, 0.f, 0.f};
        d = __builtin_amdgcn_mfma_f32_16x16x32_f16(a0, bfx[0], d, 0, 0, 0);
        if (in64) {
            v8h a1 = *(const v8h*)(Bg2 + arow + 32 + q * 8);
            d = __builtin_amdgcn_mfma_f32_16x16x32_f16(a1, bfx[1], d, 0, 0, 0);
        }
        const int sl = m;                             // SLOT index
        union { f16 x[4]; uint2 u; } pk;
        pk.x[0] = (f16)d[0]; pk.x[1] = (f16)d[1];
        pk.x[2] = (f16)d[2]; pk.x[3] = (f16)d[3];
        *(uint2*)(ubs + sl * 68 + (w << 4) + (q << 2)) = pk.u;
    }
    __syncthreads();

    // ---- epilogue: scatter acc + ub into agg by dst (f32 atomics)
#pragma unroll
    for (int j = 0; j < 4; j++) {
        const int vn = (w << 2) + j;                  // SLOT index
        const int rb = srb[vn], ct = sct[vn];
        if (ct == 0) continue;                        // wave-uniform
        int dr[4];
#pragma unroll
        for (int r = 0; r < 4; r++) {
            const int es = (q << 2) + r;
            dr[r] = (es < ct) ? dst[eix[rb + es]] : -1;
        }
#pragma unroll
        for (int ot = 0; ot < 4; ot++) {
            const float ub = (float)ubs[vn * 68 + (ot << 4) + m];
#pragma unroll
            for (int r = 0; r < 4; r++)
                if (dr[r] >= 0)
                    atomicAdd(&agg[(size_t)dr[r] * 64 + (ot << 4) + m],
                              acc[j][ot][r] + ub);
        }
    }
}

// ---------------------------------------------------------------------------
// pre[n,o] = agg[n,o] + sum_i x[n,i]*root[i,o] + bias[o]; accumulate BN stats.
__global__ __launch_bounds__(256) void pre_stats(const float* __restrict__ agg,
                                                 const float* __restrict__ x,
                                                 const float* __restrict__ root,
                                                 const float* __restrict__ bias,
                                                 float* __restrict__ pre,
                                                 float* __restrict__ stats,
                                                 int in, int inshift) {
    __shared__ float xs[4][64];
    __shared__ float lsum[64], lsq[64];
    const int o = threadIdx.x & 63, nl = threadIdx.x >> 6;
    if (threadIdx.x < 64) { lsum[threadIdx.x] = 0.f; lsq[threadIdx.x] = 0.f; }
    const float bo = bias[o];
    for (int n0 = blockIdx.x * 4; n0 < N_NODES; n0 += gridDim.x * 4) {
        __syncthreads();
        for (int idx = threadIdx.x; idx < (4 << inshift); idx += 256) {
            int r = idx >> inshift, i = idx & (in - 1);
            if (n0 + r < N_NODES) xs[r][i] = x[(size_t)(n0 + r) * in + i];
        }
        __syncthreads();
        int n = n0 + nl;
        if (n < N_NODES) {
            float acc = agg[(size_t)n * 64 + o] + bo;
#pragma unroll 8
            for (int i = 0; i < in; i++) acc += xs[nl][i] * root[i * 64 + o];
            pre[(size_t)n * 64 + o] = acc;
            atomicAdd(&lsum[o], acc);
            atomicAdd(&lsq[o], acc * acc);
        }
    }
    __syncthreads();
    if (threadIdx.x < 64) {
        atomicAdd(&stats[threadIdx.x], lsum[threadIdx.x]);
        atomicAdd(&stats[64 + threadIdx.x], lsq[threadIdx.x]);
    }
}

// ---------------------------------------------------------------------------
// BN (batch stats, biased var) + ReLU. mode 0: store xn. mode 1: segment-max pool.
__global__ __launch_bounds__(256) void bn_apply(const float* __restrict__ pre,
                                                const float* __restrict__ stats,
                                                const float* __restrict__ gamma,
                                                const float* __restrict__ beta,
                                                float* __restrict__ xn,
                                                const int* __restrict__ batch,
                                                float* __restrict__ pooled,
                                                int mode) {
    int idx = blockIdx.x * 256 + threadIdx.x;
    if (idx >= N_NODES * 64) return;
    const int o = idx & 63, n = idx >> 6;
    const float inv = 1.f / (float)N_NODES;
    float mu = stats[o] * inv;
    float var = stats[64 + o] * inv - mu * mu;
    float sc = gamma[o] * rsqrtf(var + EPS);
    float sh = beta[o] - mu * sc;
    float v = fmaxf(pre[idx] * sc + sh, 0.f);
    if (mode == 0) xn[idx] = v;
    else atomicMax((int*)&pooled[(size_t)batch[n] * 64 + o], __float_as_int(v));
}

// ---------------------------------------------------------------------------
// out[g] = pp_b2 + relu(cat(pooled[g],u[g]) @ pp_w1 + pp_b1) @ pp_w2
__global__ __launch_bounds__(64) void final_mlp(const float* __restrict__ pooled,
                                                const float* __restrict__ u,
                                                const float* __restrict__ w1,
                                                const float* __restrict__ b1,
                                                const float* __restrict__ w2,
                                                const float* __restrict__ b2,
                                                float* __restrict__ out) {
    const int g = blockIdx.x, t = threadIdx.x;
    float acc = b1[t];
#pragma unroll 8
    for (int i = 0; i < 64; i++) acc += pooled[g * 64 + i] * w1[i * 64 + t];
#pragma unroll
    for (int j = 0; j < GIN; j++) acc += u[g * GIN + j] * w1[(64 + j) * 64 + t];
    float hv = fmaxf(acc, 0.f) * w2[t];
#pragma unroll
    for (int off = 32; off > 0; off >>= 1) hv += __shfl_down(hv, off, 64);
    if (t == 0) out[g] = hv + b2[0];
}

// ---------------------------------------------------------------------------
extern "C" void kernel_launch(void* const* d_in, const int* in_sizes, int n_in,
                              void* d_out, int out_size, void* d_ws, size_t ws_size,
                              hipStream_t stream) {
    const float* x0      = (const float*)d_in[0];
    const int*   ei      = (const int*)d_in[1];
    const int*   src     = ei;
    const int*   dst     = ei + N_EDGES;
    const float* ea      = (const float*)d_in[2];
    const int*   batch   = (const int*)d_in[3];
    const float* u       = (const float*)d_in[4];
    const float* e0w1    = (const float*)d_in[5];
    const float* e0b1    = (const float*)d_in[6];
    const float* e0w2    = (const float*)d_in[7];
    const float* e0b2    = (const float*)d_in[8];
    const float* root0   = (const float*)d_in[9];
    const float* bias0   = (const float*)d_in[10];
    const float* gamma0  = (const float*)d_in[11];
    const float* beta0   = (const float*)d_in[12];
    const float* ew1     = (const float*)d_in[13];
    const float* eb1     = (const float*)d_in[14];
    const float* ew2     = (const float*)d_in[15];
    const float* eb2     = (const float*)d_in[16];
    const float* rootl   = (const float*)d_in[17];
    const float* biasl   = (const float*)d_in[18];
    const float* gammal  = (const float*)d_in[19];
    const float* betal   = (const float*)d_in[20];
    const float* pp_w1   = (const float*)d_in[21];
    const float* pp_b1   = (const float*)d_in[22];
    const float* pp_w2   = (const float*)d_in[23];
    const float* pp_b2   = (const float*)d_in[24];

    float* ws = (float*)d_ws;
    size_t off = 0;
    f16*   htp    = (f16*)(ws + off); off += (size_t)N_EDGES * KDIM / 2;
    f16*   xf     = (f16*)(ws + off); off += (size_t)N_NODES * 64 / 2;
    f16*   Bg2    = (f16*)(ws + off); off += (size_t)8256 * 64 / 2;
    float* agg    = ws + off; off += (size_t)N_NODES * 64;
    float* xa     = ws + off; off += (size_t)N_NODES * 64;
    float* xb     = ws + off; off += (size_t)N_NODES * 64;
    float* stats  = ws + off; off += 256;
    float* pooled = ws + off; off += (size_t)NG * 64;
    int*   row_ptr = (int*)(ws + off); off += 10008;
    int*   cursor  = (int*)(ws + off); off += 10000;
    int*   cnt     = (int*)(ws + off); off += 10000;
    int*   eix     = (int*)(ws + off); off += N_EDGES;
    int*   einv    = (int*)(ws + off); off += N_EDGES;
    int*   vn_node = (int*)(ws + off); off += NVMAX + 12;
    int*   vn_rb   = (int*)(ws + off); off += NVMAX + 12;
    int*   nvp     = (int*)(ws + off); off += 8;

    hipMemsetAsync(pooled, 0, (size_t)NG * 64 * 4, stream);

    const int eblocks = (N_EDGES + 255) / 256;               // 196
    const int hblocks = (N_EDGES + 127) / 128;               // 391
    const int fblocks = (NVMAX + BV - 1) / BV;               // 782 (early-exit past nv)
    const int ablocks = (N_NODES * 64 + 255) / 256;

    // src-CSR + vnode list: built once, reused by all 4 layers
    hipMemsetAsync(cnt, 0, N_NODES * 4, stream);
    csr_count<<<eblocks, 256, 0, stream>>>(src, cnt);
    csr_scan<<<1, 256, 0, stream>>>(cnt, row_ptr, cursor, vn_node, vn_rb, nvp);
    csr_fill<<<eblocks, 256, 0, stream>>>(src, cursor, eix, einv);

    struct Layer {
        const float *w1, *b1, *w2, *b2, *root, *bias, *gamma, *beta, *xin;
        float* xout; int in, inshift, mode;
    };
    Layer L[4];
    L[0] = {e0w1, e0b1, e0w2, e0b2, root0, bias0, gamma0, beta0, x0, xa, IN0, 5, 0};
    for (int l = 0; l < 3; l++) {
        const float* xin  = (l == 0) ? xa : ((l == 1) ? xb : xa);
        float*       xout = (l == 0) ? xb : ((l == 1) ? xa : nullptr);
        L[l + 1] = {ew1 + (size_t)l * EDGE_IN * KDIM, eb1 + (size_t)l * KDIM,
                    ew2 + (size_t)l * KDIM * (HID * HID), eb2 + (size_t)l * (HID * HID),
                    rootl + (size_t)l * HID * HID, biasl + (size_t)l * HID,
                    gammal + (size_t)l * HID, betal + (size_t)l * HID,
                    xin, xout, HID, 6, (l == 2) ? 1 : 0};
    }

    for (int l = 0; l < 4; l++) {
        const Layer& P = L[l];
        const int bblocks = ((8256 << P.inshift) + 255) / 256;
        ht_kernel<<<hblocks, 256, 0, stream>>>(ea, P.w1, P.b1, einv, htp);
        xconv<<<(N_NODES * P.in + 255) / 256, 256, 0, stream>>>(P.xin, xf, N_NODES * P.in);
        bconv<<<bblocks, 256, 0, stream>>>(P.w2, P.b2, Bg2, P.inshift);
        hipMemsetAsync(agg, 0, (size_t)N_NODES * 64 * 4, stream);
        hipMemsetAsync(stats, 0, 128 * 4, stream);
        fused_msg2<<<fblocks, 256, 0, stream>>>(htp, xf, Bg2, eix, row_ptr,
                                                vn_node, vn_rb, dst, agg, nvp,
                                                P.inshift);
        pre_stats<<<512, 256, 0, stream>>>(agg, P.xin, P.root, P.bias, agg, stats,
                                           P.in, P.inshift);
        bn_apply<<<ablocks, 256, 0, stream>>>(agg, stats, P.gamma, P.beta, P.xout,
                                              batch, pooled, P.mode);
    }
    final_mlp<<<NG, 64, 0, stream>>>(pooled, u, pp_w1, pp_b1, pp_w2, pp_b2,
                                     (float*)d_out);
}

// Round 11
// 769.724 us; speedup vs baseline: 1.3832x; 1.1169x over previous
//
#include <hip/hip_runtime.h>

#define N_NODES 10000
#define N_EDGES 50000
#define IN0     32
#define EDGE_IN 16
#define GIN     8
#define HID     64
#define NG      64
#define KDIM    128
#define BV      16        // virtual nodes per fused block
#define NVMAX   12500     // sum ceil(deg/16) <= (E + 15*N)/16
#define EPS     1e-5f

typedef _Float16 f16;
typedef _Float16 v8h __attribute__((ext_vector_type(8)));
typedef float    v4f __attribute__((ext_vector_type(4)));

#define HTSTR ((size_t)N_EDGES * KDIM)      // per-layer htp stride (f16)
#define BGSTR ((size_t)8256 * 64)           // per-layer Bg2 stride (f16)

// ---------------------------------------------------------------------------
// ALL 4 LAYERS in one dispatch (blockIdx.y = layer; ht depends only on
// constant inputs). htp[l][einv[e]][j] = f16(relu(ea[e]@w1_l[:,j] + b1_l[j])),
// rows permuted into src-CSR order so the fused app-phase reads are coalesced.
__global__ __launch_bounds__(256) void ht_kernel(const float* __restrict__ ea,
                                                 const float* __restrict__ e0w1,
                                                 const float* __restrict__ e0b1,
                                                 const float* __restrict__ ew1,
                                                 const float* __restrict__ eb1,
                                                 const int* __restrict__ einv,
                                                 f16* __restrict__ htp) {
    const int l = blockIdx.y;
    const float* w1 = (l == 0) ? e0w1 : ew1 + (size_t)(l - 1) * EDGE_IN * KDIM;
    const float* b1 = (l == 0) ? e0b1 : eb1 + (size_t)(l - 1) * KDIM;
    f16* out = htp + (size_t)l * HTSTR;

    __shared__ float eas[128][17];
    __shared__ f16 hl[128][136];      // 128 k-rows padded to 136 (16B-aligned rows)
    const int e0 = blockIdx.x * 128, t = threadIdx.x;
    for (int idx = t; idx < 128 * 16; idx += 256) {
        int r = idx >> 4, i = idx & 15;
        eas[r][i] = (e0 + r < N_EDGES) ? ea[(size_t)(e0 + r) * EDGE_IN + i] : 0.f;
    }
    __syncthreads();
    const int el = t & 127, jh = t >> 7;
#pragma unroll 1
    for (int jj = 0; jj < 64; jj++) {
        const int j = jh * 64 + jj;
        float acc = b1[j];
#pragma unroll
        for (int i = 0; i < EDGE_IN; i++) acc += eas[el][i] * w1[i * KDIM + j];
        hl[el][j] = (f16)fmaxf(acc, 0.f);
    }
    __syncthreads();
    for (int idx = t; idx < 128 * 16; idx += 256) {     // 16 uint4 per 128-f16 row
        const int row = idx >> 4, sg = idx & 15;
        if (e0 + row < N_EDGES) {
            uint4* dp = (uint4*)(out + (size_t)einv[e0 + row] * KDIM) + sg;
            *dp = *((const uint4*)(&hl[row][0]) + sg);
        }
    }
}

// ---------------------------------------------------------------------------
// xf[idx] = f16(x[idx])   (layer 0 input only; later layers get xf from bn_apply)
__global__ __launch_bounds__(256) void xconv(const float* __restrict__ x,
                                             f16* __restrict__ xf, int n) {
    int idx = blockIdx.x * 256 + threadIdx.x;
    if (idx < n) xf[idx] = (f16)x[idx];
}

// ---------------------------------------------------------------------------
// ALL 4 LAYERS in one dispatch (blockIdx.y = layer).
// Bg2[l][C'][i], C' = o*128 + k (k minor) for k<128: w2_l[k][i*64+o];
// rows 8192+o: b2_l[i*64+o] (the per-node bias term ub). f16.
__global__ __launch_bounds__(256) void bconv(const float* __restrict__ e0w2,
                                             const float* __restrict__ e0b2,
                                             const float* __restrict__ ew2,
                                             const float* __restrict__ eb2,
                                             f16* __restrict__ Bg2all) {
    const int l = blockIdx.y;
    const int inshift = l ? 6 : 5;
    const int in = 1 << inshift;
    const float* w2 = (l == 0) ? e0w2 : ew2 + (size_t)(l - 1) * KDIM * HID * HID;
    const float* b2 = (l == 0) ? e0b2 : eb2 + (size_t)(l - 1) * HID * HID;
    f16* Bg2 = Bg2all + (size_t)l * BGSTR;

    const int total = 8256 << inshift;
    int idx = blockIdx.x * 256 + threadIdx.x;
    if (idx >= total) return;
    const int i = idx & (in - 1), C = idx >> inshift;
    float v;
    if (C < 8192) {
        const int k = C & 127, o = C >> 7;
        v = w2[(size_t)k * (in << 6) + (i << 6) + o];
    } else {
        const int o = C - 8192;
        v = b2[(i << 6) + o];
    }
    Bg2[idx] = (f16)v;
}

// ---------------------------------------------------------------------------
// CSR over SRC (constant across layers; built once) + virtual-node list:
// vnode = (node, 16-edge subrange). nv <= NVMAX.
__global__ __launch_bounds__(256) void csr_count(const int* __restrict__ src,
                                                 int* __restrict__ cnt) {
    int e = blockIdx.x * 256 + threadIdx.x;
    if (e < N_EDGES) atomicAdd(&cnt[src[e]], 1);
}

__global__ __launch_bounds__(256) void csr_scan(const int* __restrict__ cnt,
                                                int* __restrict__ row_ptr,
                                                int* __restrict__ cursor,
                                                int* __restrict__ vn_node,
                                                int* __restrict__ vn_rb,
                                                int* __restrict__ nvp) {
    __shared__ int part[256], psum[257];
    __shared__ int vpart[256], vpsum[257];
    const int t = threadIdx.x;
    const int base = t * 40;                       // 256*40 >= 10000
    int s = 0, vs = 0;
    for (int i = 0; i < 40; i++) {
        int idx = base + i;
        if (idx < N_NODES) { int d = cnt[idx]; s += d; vs += (d + 15) >> 4; }
    }
    part[t] = s; vpart[t] = vs;
    __syncthreads();
    if (t == 0) {
        int run = 0, vrun = 0;
        for (int i = 0; i < 256; i++) {
            psum[i] = run;  run += part[i];
            vpsum[i] = vrun; vrun += vpart[i];
        }
        psum[256] = run; vpsum[256] = vrun;
    }
    __syncthreads();
    int run = psum[t], vrun = vpsum[t];
    for (int i = 0; i < 40; i++) {
        int idx = base + i;
        if (idx < N_NODES) {
            int d = cnt[idx];
            row_ptr[idx] = run; cursor[idx] = run;
            int nvn = (d + 15) >> 4;
            for (int j = 0; j < nvn; j++) {
                vn_node[vrun] = idx; vn_rb[vrun] = run + j * 16; vrun++;
            }
            run += d;
        }
    }
    if (t == 255) { row_ptr[N_NODES] = psum[256]; *nvp = vpsum[256]; }
}

__global__ __launch_bounds__(256) void csr_fill(const int* __restrict__ src,
                                                int* __restrict__ cursor,
                                                int* __restrict__ eix,
                                                int* __restrict__ einv) {
    int e = blockIdx.x * 256 + threadIdx.x;
    if (e < N_EDGES) {
        int p = atomicAdd(&cursor[src[e]], 1);
        eix[p] = e;
        einv[e] = p;
    }
}

// ---------------------------------------------------------------------------
// Node-factored NNConv (R10-passing indexing + ht chunk prefetch):
//   T[n,k,o] = sum_i xf[n,i] * w2[k,i,o]
//   msg[e,o] = sum_k ht[e,k] * T[src,k,o] + ub[src,o];  agg[dst] += msg
// ht loads for chunk c's app phase are issued BEFORE the T-phase; the pre-app
// barrier drains them, so their HBM/L2 latency hides under T-phase MFMAs.
__global__ __launch_bounds__(256, 1) void fused_msg2(const f16* __restrict__ htp,
                                                     const f16* __restrict__ xf,
                                                     const f16* __restrict__ Bg2,
                                                     const int* __restrict__ eix,
                                                     const int* __restrict__ row_ptr,
                                                     const int* __restrict__ vn_node,
                                                     const int* __restrict__ vn_rb,
                                                     const int* __restrict__ dst,
                                                     float* __restrict__ agg,
                                                     const int* __restrict__ nvp,
                                                     int inshift) {
    __shared__ f16 tcs[BV * 1024 + 32];   // [slot][(o^(slot&3))][k16] + tail pad
    __shared__ f16 ubs[BV * 68];          // [slot][o] row-padded 64->68
    __shared__ int snd[BV], srb[BV], sct[BV];

    const int t = threadIdx.x;
    const int w = t >> 6, lane = t & 63;
    const int m = lane & 15, q = lane >> 4;
    const int v0 = blockIdx.x * BV;
    const int nv = *nvp;
    if (v0 >= nv) return;
    const bool in64 = (inshift == 6);

    for (int i = t; i < BV; i += 256) {
        int v = v0 + i, n = 0, rb = 0, ct = 0;
        if (v < nv) {
            n = vn_node[v]; rb = vn_rb[v];
            int re = row_ptr[n + 1];
            ct = re - rb; if (ct > 16) ct = 16;
        }
        snd[i] = n; srb[i] = rb; sct[i] = ct;
    }
    // zero the tail pad (vn=BV-1, q>=2 lanes read it with zero-A; stale NaN
    // would poison 0*x)
    if (t < 8) *(uint2*)(tcs + BV * 1024 + t * 4) = (uint2){0u, 0u};
    __syncthreads();

    // T-phase B-fragment: xf row of slot m (N dim = the 16 slots)
    v8h bfx[2];
    {
        const size_t nb = (size_t)snd[m] << inshift;
        bfx[0] = *(const v8h*)(xf + nb + q * 8);
        if (in64) bfx[1] = *(const v8h*)(xf + nb + 32 + q * 8);
    }

    // chunk-invariant htp row pointer per j (this lane's edge slot of vnode)
    const f16* hrow[4];
#pragma unroll
    for (int j = 0; j < 4; j++) {
        const int vn = (w << 2) + j;
        const int rb = srb[vn], ct = sct[vn];
        const int es = (m < ct) ? m : (ct > 0 ? ct - 1 : 0);
        hrow[j] = htp + (size_t)(rb + es) * KDIM;
    }

    v4f acc[4][4];
#pragma unroll
    for (int j = 0; j < 4; j++)
#pragma unroll
        for (int ot = 0; ot < 4; ot++) acc[j][ot] = (v4f){0.f, 0.f, 0.f, 0.f};

    for (int c = 0; c < 8; c++) {
        // ---- prefetch this chunk's app-phase ht fragments (latency hides
        // under the T-phase; drained by the pre-app barrier)
        v8h hpre[4];
#pragma unroll
        for (int j = 0; j < 4; j++) {
            v8h tmp;
#pragma unroll
            for (int z = 0; z < 8; z++) tmp[z] = (f16)0.f;
            if (q < 2)      // lanes q>=2 are k 16..31 of the MFMA: zero (K=16 pad)
                tmp = *(const v8h*)(hrow[j] + (c << 4) + q * 8);
            hpre[j] = tmp;
        }
        // ---- T-phase: wave w computes o in [w*16, w*16+16), all 16 slots.
        // D (16x16): row = q*4+reg -> k within chunk, col = m -> slot.
#pragma unroll 4
        for (int ol = 0; ol < 16; ol++) {
            const int o = (w << 4) + ol;
            const size_t arow = ((size_t)(o * 128 + (c << 4) + m)) << inshift;
            v8h a0 = *(const v8h*)(Bg2 + arow + q * 8);
            v8h a1;
            if (in64) a1 = *(const v8h*)(Bg2 + arow + 32 + q * 8);
            v4f d = (v4f){0.f, 0.f, 0.f, 0.f};
            d = __builtin_amdgcn_mfma_f32_16x16x32_f16(a0, bfx[0], d, 0, 0, 0);
            if (in64)
                d = __builtin_amdgcn_mfma_f32_16x16x32_f16(a1, bfx[1], d, 0, 0, 0);
            const int sl = m;                         // SLOT index
            union { f16 x[4]; uint2 u; } pk;
            pk.x[0] = (f16)d[0]; pk.x[1] = (f16)d[1];
            pk.x[2] = (f16)d[2]; pk.x[3] = (f16)d[3];
            *(uint2*)(tcs + sl * 1024 + ((o ^ (sl & 3)) << 4) + (q << 2)) = pk.u;
        }
        __syncthreads();
        // ---- app-phase: wave w applies vnode slots w*4 .. w*4+3
#pragma unroll
        for (int j = 0; j < 4; j++) {
            const int vn = (w << 2) + j;              // SLOT index 0..15
            const f16* tb = tcs + vn * 1024;
            const int nx = vn & 3;
#pragma unroll
            for (int ot = 0; ot < 4; ot++) {
                v8h hb = *(const v8h*)(tb + ((((ot << 4) + m) ^ nx) << 4) + (q << 3));
                acc[j][ot] = __builtin_amdgcn_mfma_f32_16x16x32_f16(hpre[j], hb,
                                                                    acc[j][ot], 0, 0, 0);
            }
        }
        __syncthreads();
    }

    // ---- ub mini-chunk: ub[slot][o] = sum_i xf[n,i] b2[i,o] (Bg2 rows 8192+o)
    {
        const size_t arow = ((size_t)(8192 + (w << 4) + m)) << inshift;
        v8h a0 = *(const v8h*)(Bg2 + arow + q * 8);
        v4f d = (v4f){0.f, 0.f, 0.f, 0.f};
        d = __builtin_amdgcn_mfma_f32_16x16x32_f16(a0, bfx[0], d, 0, 0, 0);
        if (in64) {
            v8h a1 = *(const v8h*)(Bg2 + arow + 32 + q * 8);
            d = __builtin_amdgcn_mfma_f32_16x16x32_f16(a1, bfx[1], d, 0, 0, 0);
        }
        const int sl = m;                             // SLOT index
        union { f16 x[4]; uint2 u; } pk;
        pk.x[0] = (f16)d[0]; pk.x[1] = (f16)d[1];
        pk.x[2] = (f16)d[2]; pk.x[3] = (f16)d[3];
        *(uint2*)(ubs + sl * 68 + (w << 4) + (q << 2)) = pk.u;
    }
    __syncthreads();

    // ---- epilogue: scatter acc + ub into agg by dst (f32 atomics)
#pragma unroll
    for (int j = 0; j < 4; j++) {
        const int vn = (w << 2) + j;                  // SLOT index
        const int rb = srb[vn], ct = sct[vn];
        if (ct == 0) continue;                        // wave-uniform
        int dr[4];
#pragma unroll
        for (int r = 0; r < 4; r++) {
            const int es = (q << 2) + r;
            dr[r] = (es < ct) ? dst[eix[rb + es]] : -1;
        }
#pragma unroll
        for (int ot = 0; ot < 4; ot++) {
            const float ub = (float)ubs[vn * 68 + (ot << 4) + m];
#pragma unroll
            for (int r = 0; r < 4; r++)
                if (dr[r] >= 0)
                    atomicAdd(&agg[(size_t)dr[r] * 64 + (ot << 4) + m],
                              acc[j][ot][r] + ub);
        }
    }
}

// ---------------------------------------------------------------------------
// pre[n,o] = agg[n,o] + sum_i x[n,i]*root[i,o] + bias[o]; accumulate BN stats.
__global__ __launch_bounds__(256) void pre_stats(const float* __restrict__ agg,
                                                 const float* __restrict__ x,
                                                 const float* __restrict__ root,
                                                 const float* __restrict__ bias,
                                                 float* __restrict__ pre,
                                                 float* __restrict__ stats,
                                                 int in, int inshift) {
    __shared__ float xs[4][64];
    __shared__ float lsum[64], lsq[64];
    const int o = threadIdx.x & 63, nl = threadIdx.x >> 6;
    if (threadIdx.x < 64) { lsum[threadIdx.x] = 0.f; lsq[threadIdx.x] = 0.f; }
    const float bo = bias[o];
    for (int n0 = blockIdx.x * 4; n0 < N_NODES; n0 += gridDim.x * 4) {
        __syncthreads();
        for (int idx = threadIdx.x; idx < (4 << inshift); idx += 256) {
            int r = idx >> inshift, i = idx & (in - 1);
            if (n0 + r < N_NODES) xs[r][i] = x[(size_t)(n0 + r) * in + i];
        }
        __syncthreads();
        int n = n0 + nl;
        if (n < N_NODES) {
            float acc = agg[(size_t)n * 64 + o] + bo;
#pragma unroll 8
            for (int i = 0; i < in; i++) acc += xs[nl][i] * root[i * 64 + o];
            pre[(size_t)n * 64 + o] = acc;
            atomicAdd(&lsum[o], acc);
            atomicAdd(&lsq[o], acc * acc);
        }
    }
    __syncthreads();
    if (threadIdx.x < 64) {
        atomicAdd(&stats[threadIdx.x], lsum[threadIdx.x]);
        atomicAdd(&stats[64 + threadIdx.x], lsq[threadIdx.x]);
    }
}

// ---------------------------------------------------------------------------
// BN (batch stats, biased var) + ReLU. Zeroes pre(=agg) after its single read
// (replaces the per-layer agg memset). mode 0: store xn (f32) + xf (f16, input
// to next layer's fused T-phase). mode 1: segment-max pool.
__global__ __launch_bounds__(256) void bn_apply(float* __restrict__ pre,
                                                const float* __restrict__ stats,
                                                const float* __restrict__ gamma,
                                                const float* __restrict__ beta,
                                                float* __restrict__ xn,
                                                f16* __restrict__ xfo,
                                                const int* __restrict__ batch,
                                                float* __restrict__ pooled,
                                                int mode) {
    int idx = blockIdx.x * 256 + threadIdx.x;
    if (idx >= N_NODES * 64) return;
    const int o = idx & 63, n = idx >> 6;
    const float inv = 1.f / (float)N_NODES;
    float mu = stats[o] * inv;
    float var = stats[64 + o] * inv - mu * mu;
    float sc = gamma[o] * rsqrtf(var + EPS);
    float sh = beta[o] - mu * sc;
    float p = pre[idx];
    pre[idx] = 0.f;                     // agg zeroed for the next layer's fused
    float v = fmaxf(p * sc + sh, 0.f);
    if (mode == 0) { xn[idx] = v; xfo[idx] = (f16)v; }
    else atomicMax((int*)&pooled[(size_t)batch[n] * 64 + o], __float_as_int(v));
}

// ---------------------------------------------------------------------------
// out[g] = pp_b2 + relu(cat(pooled[g],u[g]) @ pp_w1 + pp_b1) @ pp_w2
__global__ __launch_bounds__(64) void final_mlp(const float* __restrict__ pooled,
                                                const float* __restrict__ u,
                                                const float* __restrict__ w1,
                                                const float* __restrict__ b1,
                                                const float* __restrict__ w2,
                                                const float* __restrict__ b2,
                                                float* __restrict__ out) {
    const int g = blockIdx.x, t = threadIdx.x;
    float acc = b1[t];
#pragma unroll 8
    for (int i = 0; i < 64; i++) acc += pooled[g * 64 + i] * w1[i * 64 + t];
#pragma unroll
    for (int j = 0; j < GIN; j++) acc += u[g * GIN + j] * w1[(64 + j) * 64 + t];
    float hv = fmaxf(acc, 0.f) * w2[t];
#pragma unroll
    for (int off = 32; off > 0; off >>= 1) hv += __shfl_down(hv, off, 64);
    if (t == 0) out[g] = hv + b2[0];
}

// ---------------------------------------------------------------------------
extern "C" void kernel_launch(void* const* d_in, const int* in_sizes, int n_in,
                              void* d_out, int out_size, void* d_ws, size_t ws_size,
                              hipStream_t stream) {
    const float* x0      = (const float*)d_in[0];
    const int*   ei      = (const int*)d_in[1];
    const int*   src     = ei;
    const int*   dst     = ei + N_EDGES;
    const float* ea      = (const float*)d_in[2];
    const int*   batch   = (const int*)d_in[3];
    const float* u       = (const float*)d_in[4];
    const float* e0w1    = (const float*)d_in[5];
    const float* e0b1    = (const float*)d_in[6];
    const float* e0w2    = (const float*)d_in[7];
    const float* e0b2    = (const float*)d_in[8];
    const float* root0   = (const float*)d_in[9];
    const float* bias0   = (const float*)d_in[10];
    const float* gamma0  = (const float*)d_in[11];
    const float* beta0   = (const float*)d_in[12];
    const float* ew1     = (const float*)d_in[13];
    const float* eb1     = (const float*)d_in[14];
    const float* ew2     = (const float*)d_in[15];
    const float* eb2     = (const float*)d_in[16];
    const float* rootl   = (const float*)d_in[17];
    const float* biasl   = (const float*)d_in[18];
    const float* gammal  = (const float*)d_in[19];
    const float* betal   = (const float*)d_in[20];
    const float* pp_w1   = (const float*)d_in[21];
    const float* pp_b1   = (const float*)d_in[22];
    const float* pp_w2   = (const float*)d_in[23];
    const float* pp_b2   = (const float*)d_in[24];

    float* ws = (float*)d_ws;
    size_t off = 0;
    f16*   htp    = (f16*)(ws + off); off += 4 * HTSTR / 2;        // 51.2 MB
    f16*   xf     = (f16*)(ws + off); off += (size_t)N_NODES * 64 / 2;
    f16*   Bg2    = (f16*)(ws + off); off += 4 * BGSTR / 2;        // 4.2 MB
    float* agg    = ws + off; off += (size_t)N_NODES * 64;
    float* xa     = ws + off; off += (size_t)N_NODES * 64;
    float* xb     = ws + off; off += (size_t)N_NODES * 64;
    float* stats  = ws + off; off += 4 * 128 + 64;
    float* pooled = ws + off; off += (size_t)NG * 64;
    int*   row_ptr = (int*)(ws + off); off += 10008;
    int*   cursor  = (int*)(ws + off); off += 10000;
    int*   cnt     = (int*)(ws + off); off += 10000;
    int*   eix     = (int*)(ws + off); off += N_EDGES;
    int*   einv    = (int*)(ws + off); off += N_EDGES;
    int*   vn_node = (int*)(ws + off); off += NVMAX + 12;
    int*   vn_rb   = (int*)(ws + off); off += NVMAX + 12;
    int*   nvp     = (int*)(ws + off); off += 8;

    const int eblocks = (N_EDGES + 255) / 256;               // 196
    const int hblocks = (N_EDGES + 127) / 128;               // 391
    const int bblocks = ((8256 << 6) + 255) / 256;           // 2064
    const int fblocks = (NVMAX + BV - 1) / BV;               // 782
    const int ablocks = (N_NODES * 64 + 255) / 256;

    // ---- head: layer-independent work, once
    hipMemsetAsync(pooled, 0, (size_t)NG * 64 * 4, stream);
    hipMemsetAsync(agg, 0, (size_t)N_NODES * 64 * 4, stream);
    hipMemsetAsync(stats, 0, 4 * 128 * 4, stream);
    hipMemsetAsync(cnt, 0, N_NODES * 4, stream);
    csr_count<<<eblocks, 256, 0, stream>>>(src, cnt);
    csr_scan<<<1, 256, 0, stream>>>(cnt, row_ptr, cursor, vn_node, vn_rb, nvp);
    csr_fill<<<eblocks, 256, 0, stream>>>(src, cursor, eix, einv);
    ht_kernel<<<dim3(hblocks, 4), 256, 0, stream>>>(ea, e0w1, e0b1, ew1, eb1,
                                                    einv, htp);
    bconv<<<dim3(bblocks, 4), 256, 0, stream>>>(e0w2, e0b2, ew2, eb2, Bg2);
    xconv<<<(N_NODES * IN0 + 255) / 256, 256, 0, stream>>>(x0, xf, N_NODES * IN0);

    struct Layer {
        const float *root, *bias, *gamma, *beta, *xin;
        float* xout; int in, inshift, mode;
    };
    Layer L[4];
    L[0] = {root0, bias0, gamma0, beta0, x0, xa, IN0, 5, 0};
    for (int l = 0; l < 3; l++) {
        const float* xin  = (l == 0) ? xa : ((l == 1) ? xb : xa);
        float*       xout = (l == 0) ? xb : ((l == 1) ? xa : nullptr);
        L[l + 1] = {rootl + (size_t)l * HID * HID, biasl + (size_t)l * HID,
                    gammal + (size_t)l * HID, betal + (size_t)l * HID,
                    xin, xout, HID, 6, (l == 2) ? 1 : 0};
    }

    // ---- per-layer critical path: fused -> pre_stats -> bn_apply
    for (int l = 0; l < 4; l++) {
        const Layer& P = L[l];
        fused_msg2<<<fblocks, 256, 0, stream>>>(htp + (size_t)l * HTSTR, xf,
                                                Bg2 + (size_t)l * BGSTR, eix,
                                                row_ptr, vn_node, vn_rb, dst,
                                                agg, nvp, P.inshift);
        pre_stats<<<512, 256, 0, stream>>>(agg, P.xin, P.root, P.bias, agg,
                                           stats + l * 128, P.in, P.inshift);
        bn_apply<<<ablocks, 256, 0, stream>>>(agg, stats + l * 128, P.gamma,
                                              P.beta, P.xout, xf, batch, pooled,
                                              P.mode);
    }
    final_mlp<<<NG, 64, 0, stream>>>(pooled, u, pp_w1, pp_b1, pp_w2, pp_b2,
                                     (float*)d_out);
}